// Round 7
// baseline (208.882 us; speedup 1.0000x reference)
//
#include <hip/hip_runtime.h>
#include <stdint.h>

#define AS1q __attribute__((address_space(1)))
#define AS3q __attribute__((address_space(3)))

typedef unsigned short US;
typedef __bf16 bf16x8 __attribute__((ext_vector_type(8)));
typedef float f32x4 __attribute__((ext_vector_type(4)));
typedef float f32x16 __attribute__((ext_vector_type(16)));
typedef float f32x2 __attribute__((ext_vector_type(2)));
typedef __bf16 bf16x2 __attribute__((ext_vector_type(2)));

#define LOG2E 1.44269504088896340736f

__device__ __forceinline__ US f2bf(float f) {
  union { float f; uint32_t u; } c; c.f = f;
  uint32_t u = c.u;
  return (US)((u + 0x7fffu + ((u >> 16) & 1u)) >> 16);
}

__device__ __forceinline__ bf16x8 asb(uint4 u) {
  union { uint4 u; bf16x8 b; } c; c.u = u; return c.b;
}

__device__ __forceinline__ void gload16(const void* g, void* l) {
  __builtin_amdgcn_global_load_lds((AS1q void*)(void*)g, (AS3q void*)l, 16, 0, 0);
}

// ------------- prep: fused q/k/v fp32->bf16 + 4 weight transposes -------------
__global__ void prep_kernel(const float* __restrict__ q, const float* __restrict__ k,
                            const float* __restrict__ v,
                            const float* __restrict__ w0, const float* __restrict__ w1,
                            const float* __restrict__ w2, const float* __restrict__ w3,
                            US* __restrict__ qb, US* __restrict__ kb, US* __restrict__ vb,
                            US* __restrict__ t0, US* __restrict__ t1,
                            US* __restrict__ t2, US* __restrict__ t3) {
  __shared__ US T[64 * 68];
  const int bx = blockIdx.x;
  const int t = threadIdx.x;
  if (bx < 6144) {
    const int ten = bx >> 11, chunk = bx & 2047;
    const float* s; US* d;
    if (ten == 0)      { s = q; d = qb; }
    else if (ten == 1) { s = k; d = kb; }
    else               { s = v; d = vb; }
    int i = (chunk * 256 + t) * 8;
    float4 f0 = *(const float4*)&s[i];
    float4 f1 = *(const float4*)&s[i + 4];
    ushort4 u0, u1;
    u0.x = f2bf(f0.x); u0.y = f2bf(f0.y); u0.z = f2bf(f0.z); u0.w = f2bf(f0.w);
    u1.x = f2bf(f1.x); u1.y = f2bf(f1.y); u1.z = f2bf(f1.z); u1.w = f2bf(f1.w);
    *(ushort4*)&d[i] = u0;
    *(ushort4*)&d[i + 4] = u1;
    return;
  }
  const int idx = bx - 6144;
  const int wsel = idx >> 8, rem = idx & 255;
  const int n0 = (rem & 15) * 64, k0 = (rem >> 4) * 64;
  const float* W; US* Wt;
  if (wsel == 0)      { W = w0; Wt = t0; }
  else if (wsel == 1) { W = w1; Wt = t1; }
  else if (wsel == 2) { W = w2; Wt = t2; }
  else                { W = w3; Wt = t3; }
#pragma unroll
  for (int it = 0; it < 4; ++it) {
    int p = t + it * 256;
    int row = p >> 4, c4 = (p & 15) * 4;
    float4 f = *(const float4*)&W[(k0 + row) * 1024 + n0 + c4];
    ushort4 u;
    u.x = f2bf(f.x); u.y = f2bf(f.y); u.z = f2bf(f.z); u.w = f2bf(f.w);
    *(ushort4*)&T[row * 68 + c4] = u;
  }
  __syncthreads();
#pragma unroll
  for (int it = 0; it < 4; ++it) {
    int p = t + it * 256;
    int rn = p >> 4, ck = (p & 15) * 4;
    ushort4 o;
    o.x = T[(ck + 0) * 68 + rn];
    o.y = T[(ck + 1) * 68 + rn];
    o.z = T[(ck + 2) * 68 + rn];
    o.w = T[(ck + 3) * 68 + rn];
    *(ushort4*)&Wt[(n0 + rn) * 1024 + k0 + ck] = o;
  }
}

// ------------- GEMM core: 128x128 tile, BK=32, m97-style global_load_lds -------------
template <bool SWAP>
__device__ __forceinline__ void gemm_core(const US* A, const US* Wt,
                                          int m0, int n0, US* As, US* Bs,
                                          f32x4 acc[4][4]) {
  const int tid = threadIdx.x;
  const int wave = tid >> 6, lane = tid & 63;
  const int quad = lane >> 4, l16 = lane & 15;
  const int wm = wave >> 1, wn = wave & 1;
#pragma unroll
  for (int i = 0; i < 4; ++i)
#pragma unroll
    for (int j = 0; j < 4; ++j) acc[i][j] = (f32x4)0.0f;
  const int p = wave * 64 + lane;
  const int arow0 = p >> 2, koff = (p & 3) * 8;
  for (int k0 = 0; k0 < 1024; k0 += 32) {
    gload16(A + (m0 + arow0) * 1024 + k0 + koff, As + wave * 512);
    gload16(A + (m0 + arow0 + 64) * 1024 + k0 + koff, As + 2048 + wave * 512);
    gload16(Wt + (n0 + arow0) * 1024 + k0 + koff, Bs + wave * 512);
    gload16(Wt + (n0 + arow0 + 64) * 1024 + k0 + koff, Bs + 2048 + wave * 512);
    __syncthreads();
    uint4 af[4], bf_[4];
#pragma unroll
    for (int mt = 0; mt < 4; ++mt)
      af[mt] = *(const uint4*)&As[(wm * 64 + mt * 16 + l16) * 32 + quad * 8];
#pragma unroll
    for (int nt = 0; nt < 4; ++nt)
      bf_[nt] = *(const uint4*)&Bs[(wn * 64 + nt * 16 + l16) * 32 + quad * 8];
#pragma unroll
    for (int i = 0; i < 4; ++i)
#pragma unroll
      for (int j = 0; j < 4; ++j) {
        if (SWAP)
          acc[i][j] = __builtin_amdgcn_mfma_f32_16x16x32_bf16(asb(bf_[i]), asb(af[j]),
                                                              acc[i][j], 0, 0, 0);
        else
          acc[i][j] = __builtin_amdgcn_mfma_f32_16x16x32_bf16(asb(af[i]), asb(bf_[j]),
                                                              acc[i][j], 0, 0, 0);
      }
    __syncthreads();
  }
}

// Fused QKV projection (N=3072). Q is scaled by log2(e) so attn can use raw exp2.
__global__ __launch_bounds__(256, 4) void gemm_qkv_kernel(
    const US* __restrict__ qb, const US* __restrict__ kb, const US* __restrict__ vb,
    const US* __restrict__ wfT,
    const float* __restrict__ bq, const float* __restrict__ bk, const float* __restrict__ bv,
    US* __restrict__ qh, US* __restrict__ kh, US* __restrict__ vt) {
  __shared__ __align__(16) US As[4096], Bs[4096];
  const int m0 = blockIdx.x * 128, n0 = blockIdx.y * 128;
  const int which = n0 >> 10;
  const int nl0 = n0 & 1023;
  const US* A = (which == 0) ? qb : (which == 1) ? kb : vb;
  const float* bias = (which == 0) ? bq : (which == 1) ? bk : bv;
  const int tid = threadIdx.x, wave = tid >> 6, lane = tid & 63;
  const int quad = lane >> 4, l16 = lane & 15;
  const int wm = wave >> 1, wn = wave & 1;
  f32x4 acc[4][4];
  if (which == 2) {
    gemm_core<true>(A, wfT, m0, n0, As, Bs, acc);
#pragma unroll
    for (int nt = 0; nt < 4; ++nt) {
      int dg = nl0 + wn * 64 + nt * 16 + quad * 4;
#pragma unroll
      for (int r = 0; r < 4; ++r) {
        int d = dg + r;
        float bval = bias[d];
        int hh = d >> 6, dd = d & 63;
#pragma unroll
        for (int mt = 0; mt < 4; ++mt) {
          int sg = m0 + wm * 64 + mt * 16;
          int bb = sg >> 11, ss = sg & 2047;
          vt[(((size_t)bb * 16 + hh) * 64 + dd) * 2048 + ss + l16] =
              f2bf(acc[nt][mt][r] + bval);
        }
      }
    }
  } else {
    gemm_core<false>(A, wfT, m0, n0, As, Bs, acc);
    US* O = (which == 0) ? qh : kh;
    const float scale = (which == 0) ? LOG2E : 1.0f;
#pragma unroll
    for (int nt = 0; nt < 4; ++nt) {
      int nl = nl0 + wn * 64 + nt * 16 + l16;
      float bval = bias[nl];
      int hh = nl >> 6, d = nl & 63;
#pragma unroll
      for (int mt = 0; mt < 4; ++mt) {
#pragma unroll
        for (int r = 0; r < 4; ++r) {
          int m = m0 + wm * 64 + mt * 16 + quad * 4 + r;
          int bb = m >> 11, s = m & 2047;
          O[((bb * 16 + hh) * 2048 + s) * 64 + d] = f2bf((acc[mt][nt][r] + bval) * scale);
        }
      }
    }
  }
}

// Output projection: ao bf16 [4096][1024] @ woT + bo -> fp32 out
__global__ __launch_bounds__(256, 4) void gemm_out_kernel(
    const US* __restrict__ ao, const US* __restrict__ woT,
    const float* __restrict__ bo, float* __restrict__ out) {
  __shared__ __align__(16) US As[4096], Bs[2048];
  const int m0 = blockIdx.x * 128, n0 = blockIdx.y * 64;
  const int tid = threadIdx.x;
  const int wave = tid >> 6, lane = tid & 63;
  const int quad = lane >> 4, l16 = lane & 15;
  f32x4 acc[2][4];
#pragma unroll
  for (int i = 0; i < 2; ++i)
#pragma unroll
    for (int j = 0; j < 4; ++j) acc[i][j] = (f32x4)0.0f;
  const int arow0 = tid >> 2, koff = (tid & 3) * 8;
  for (int k0 = 0; k0 < 1024; k0 += 32) {
    gload16(ao + (m0 + arow0) * 1024 + k0 + koff, As + wave * 512);
    gload16(ao + (m0 + arow0 + 64) * 1024 + k0 + koff, As + 2048 + wave * 512);
    gload16(woT + (n0 + arow0) * 1024 + k0 + koff, Bs + wave * 512);
    __syncthreads();
    uint4 af[2], bf_[4];
#pragma unroll
    for (int mt = 0; mt < 2; ++mt)
      af[mt] = *(const uint4*)&As[(wave * 32 + mt * 16 + l16) * 32 + quad * 8];
#pragma unroll
    for (int nt = 0; nt < 4; ++nt)
      bf_[nt] = *(const uint4*)&Bs[(nt * 16 + l16) * 32 + quad * 8];
#pragma unroll
    for (int mt = 0; mt < 2; ++mt)
#pragma unroll
      for (int nt = 0; nt < 4; ++nt)
        acc[mt][nt] = __builtin_amdgcn_mfma_f32_16x16x32_bf16(asb(af[mt]), asb(bf_[nt]),
                                                              acc[mt][nt], 0, 0, 0);
    __syncthreads();
  }
#pragma unroll
  for (int nt = 0; nt < 4; ++nt) {
    int n = n0 + nt * 16 + l16;
    float bval = bo[n];
#pragma unroll
    for (int mt = 0; mt < 2; ++mt) {
#pragma unroll
      for (int r = 0; r < 4; ++r) {
        int m = m0 + wave * 32 + mt * 16 + quad * 4 + r;
        out[m * 1024 + n] = acc[mt][nt][r] + bval;
      }
    }
  }
}

// ------------- causal attention: 256 thr, 32x32x16 MFMA, split-K, 24 groups ----------
// qh (pre-scaled by log2e)/kh: [bh][s][64]; vt: [bh][64][s]; aout: [b*s][1024] bf16
// waves: w_m in {0,1} owns 32 q-rows; w_k in {0,1} owns 32 keys.
// C-layout 32x32: col=lane&31, row=4*(lane>>5)+8*(reg>>2)+(reg&3).
__global__ __launch_bounds__(256, 3) void attn_kernel(
    const US* __restrict__ qh, const US* __restrict__ kh,
    const US* __restrict__ vt, US* __restrict__ aout) {
  __shared__ __align__(16) US Ks[2][4096];
  __shared__ __align__(16) US Vs[2][4096];
  __shared__ __align__(16) union UU {
    struct { US Qs[4096]; US Ps[4][1280]; } s;   // Ps per wave: [32 q][40 pitch]
    struct { float Oex[64][65]; float lEx[64]; } e;
  } u;
  const int tid = threadIdx.x;
  const int wave = tid >> 6, lane = tid & 63;
  const int l31 = lane & 31, lh = lane >> 5;
  const int w_m = wave & 1, w_k = wave >> 1;
  const int bh = blockIdx.x;
  const int b = bh >> 4, h = bh & 15;
  const int g = blockIdx.y;

  int t0, t1;
  if (g < 11)      { t0 = 31 - g; t1 = -1; }
  else if (g < 19) { int j = g - 11; t0 = 16 - j; t1 = j; }
  else if (g < 23) { t0 = 17 + (g - 19); t1 = -1; }
  else             { t0 = 8; t1 = -1; }

  // staging: 256 threads cover a 64x64 bf16 tile in 2 rounds (xor-swizzled 16B chunks)
  // LDS dest is wave-uniform base + lane*16B -> thread tid lands at US offset tid*8
  // when base = wave*512 (round 1) / 2048 + wave*512 (round 2).
  const int p1 = tid, p2 = tid + 256;
  const int row1 = p1 >> 3, c1 = (p1 & 7) ^ (row1 & 7);
  const int row2 = p2 >> 3, c2 = (p2 & 7) ^ (row2 & 7);

  const US* gkb = kh + (size_t)bh * 2048 * 64;
  const US* gvb = vt + (size_t)bh * 64 * 2048;

  for (int ei = 0; ei < 2; ++ei) {
    const int qt = ei ? t1 : t0;
    if (qt < 0) break;
    const int q0 = qt * 64;
    __syncthreads();
    {
      const US* gq = qh + ((size_t)bh * 2048 + q0) * 64;
      gload16(gq + row1 * 64 + c1 * 8, u.s.Qs + wave * 512);
      gload16(gq + row2 * 64 + c2 * 8, u.s.Qs + 2048 + wave * 512);
      gload16(gkb + row1 * 64 + c1 * 8, Ks[0] + wave * 512);
      gload16(gkb + row2 * 64 + c2 * 8, Ks[0] + 2048 + wave * 512);
      gload16(gvb + row1 * 2048 + c1 * 8, Vs[0] + wave * 512);
      gload16(gvb + row2 * 2048 + c2 * 8, Vs[0] + 2048 + wave * 512);
    }
    __syncthreads();

    // hoist Q fragments: A[m=q=l31][k=d], d-chunk dc -> logical chunk dc*2+lh
    const int ql = w_m * 32 + l31;
    uint4 aq[4];
#pragma unroll
    for (int dc = 0; dc < 4; ++dc)
      aq[dc] = *(const uint4*)&u.s.Qs[ql * 64 + (((dc * 2 + lh) ^ (ql & 7)) * 8)];

    float l_part[16];
#pragma unroll
    for (int r = 0; r < 16; ++r) l_part[r] = 0.0f;
    f32x16 Of0 = (f32x16)0.0f, Of1 = (f32x16)0.0f;

    US* pw = u.s.Ps[wave];
    const int kl = w_k * 32 + l31;

    for (int kt = 0; kt <= qt; ++kt) {
      const int cb = kt & 1;
      if (kt) __syncthreads();
      if (kt < qt) {
        const US* gk = gkb + (kt + 1) * 64 * 64;
        const US* gv = gvb + (kt + 1) * 64;
        gload16(gk + row1 * 64 + c1 * 8, Ks[cb ^ 1] + wave * 512);
        gload16(gk + row2 * 64 + c2 * 8, Ks[cb ^ 1] + 2048 + wave * 512);
        gload16(gv + row1 * 2048 + c1 * 8, Vs[cb ^ 1] + wave * 512);
        gload16(gv + row2 * 2048 + c2 * 8, Vs[cb ^ 1] + 2048 + wave * 512);
      }
      const US* Kc = Ks[cb];
      const US* Vc = Vs[cb];

      // S[32q][32k] over d=64: 4 MFMAs; B-frag = K[key=l31][d-chunk]
      f32x16 sacc = (f32x16)0.0f;
#pragma unroll
      for (int dc = 0; dc < 4; ++dc) {
        uint4 kb_ = *(const uint4*)&Kc[kl * 64 + (((dc * 2 + lh) ^ (kl & 7)) * 8)];
        sacc = __builtin_amdgcn_mfma_f32_32x32x16_bf16(asb(aq[dc]), asb(kb_), sacc, 0, 0, 0);
      }
      if (kt == qt) {
        int gcol = q0 + w_k * 32 + l31;  // k0 == q0 on diagonal
#pragma unroll
        for (int r = 0; r < 16; ++r) {
          int grow = q0 + w_m * 32 + 4 * lh + 8 * (r >> 2) + (r & 3);
          if (gcol > grow) sacc[r] = -1e30f;
        }
      }

      // exp2 (Q pre-scaled by log2e) -> P row-major [q][40]; l in fp32
#pragma unroll
      for (int r = 0; r < 16; r += 2) {
        float e0 = __builtin_amdgcn_exp2f(sacc[r]);
        float e1 = __builtin_amdgcn_exp2f(sacc[r + 1]);
        l_part[r] += e0;
        l_part[r + 1] += e1;
        f32x2 fv; fv[0] = e0; fv[1] = e1;
        bf16x2 bv2 = __builtin_convertvector(fv, bf16x2);
        union { bf16x2 b; ushort2 u; } cc; cc.b = bv2;
        int row0 = 4 * lh + 8 * (r >> 2) + (r & 3);
        pw[row0 * 40 + l31] = cc.u.x;
        pw[(row0 + 1) * 40 + l31] = cc.u.y;
      }
      __asm__ volatile("s_waitcnt lgkmcnt(0)" ::: "memory");

      // O += P V : A-frag = P[q=l31][key-chunk], B-frag = V[key][d] = Vs[d-row][key]
      uint4 ap0 = *(const uint4*)&pw[l31 * 40 + lh * 8];
      uint4 ap1 = *(const uint4*)&pw[l31 * 40 + 16 + lh * 8];
#pragma unroll
      for (int dh = 0; dh < 2; ++dh) {
        int vrow = dh * 32 + l31;
        uint4 bv0 = *(const uint4*)&Vc[vrow * 64 + (((w_k * 4 + lh) ^ (vrow & 7)) * 8)];
        uint4 bv1 = *(const uint4*)&Vc[vrow * 64 + (((w_k * 4 + 2 + lh) ^ (vrow & 7)) * 8)];
        if (dh == 0) {
          Of0 = __builtin_amdgcn_mfma_f32_32x32x16_bf16(asb(ap0), asb(bv0), Of0, 0, 0, 0);
          Of0 = __builtin_amdgcn_mfma_f32_32x32x16_bf16(asb(ap1), asb(bv1), Of0, 0, 0, 0);
        } else {
          Of1 = __builtin_amdgcn_mfma_f32_32x32x16_bf16(asb(ap0), asb(bv0), Of1, 0, 0, 0);
          Of1 = __builtin_amdgcn_mfma_f32_32x32x16_bf16(asb(ap1), asb(bv1), Of1, 0, 0, 0);
        }
      }
    }

    // reduce l over the 32 column-lanes (same rows across an l31 group)
#pragma unroll
    for (int r = 0; r < 16; ++r) {
#pragma unroll
      for (int off = 1; off < 32; off <<= 1)
        l_part[r] += __shfl_xor(l_part[r], off, 64);
    }

    __syncthreads();  // all waves done with Qs/Ps; overlay epilogue exchange
    if (w_k == 1) {
#pragma unroll
      for (int r = 0; r < 16; ++r) {
        int row = w_m * 32 + 4 * lh + 8 * (r >> 2) + (r & 3);
        u.e.Oex[row][l31] = Of0[r];
        u.e.Oex[row][32 + l31] = Of1[r];
        if (l31 == 0) u.e.lEx[row] = l_part[r];
      }
    }
    __syncthreads();
    if (w_k == 0) {
#pragma unroll
      for (int r = 0; r < 16; ++r) {
        int rl = 4 * lh + 8 * (r >> 2) + (r & 3);
        int row = w_m * 32 + rl;
        float ltot = l_part[r] + u.e.lEx[row];
        float inv = 1.0f / ltot;
        int grow = q0 + row;
        float o0 = Of0[r] + u.e.Oex[row][l31];
        float o1 = Of1[r] + u.e.Oex[row][32 + l31];
        US* dst = aout + ((size_t)b * 2048 + grow) * 1024 + h * 64;
        dst[l31] = f2bf(o0 * inv);
        dst[32 + l31] = f2bf(o1 * inv);
      }
    }
  }
}

extern "C" void kernel_launch(void* const* d_in, const int* in_sizes, int n_in,
                              void* d_out, int out_size, void* d_ws, size_t ws_size,
                              hipStream_t stream) {
  const float* q  = (const float*)d_in[0];
  const float* k  = (const float*)d_in[1];
  const float* v  = (const float*)d_in[2];
  const float* wq = (const float*)d_in[3];
  const float* bq = (const float*)d_in[4];
  const float* wk = (const float*)d_in[5];
  const float* bk = (const float*)d_in[6];
  const float* wv = (const float*)d_in[7];
  const float* bv = (const float*)d_in[8];
  const float* wo = (const float*)d_in[9];
  const float* bo = (const float*)d_in[10];
  float* out = (float*)d_out;

  char* ws = (char*)d_ws;
  const size_t MB = 1024 * 1024;
  US* qb  = (US*)(ws + 0 * MB);
  US* kb  = (US*)(ws + 8 * MB);
  US* vb  = (US*)(ws + 16 * MB);
  US* wqT = (US*)(ws + 24 * MB);  // wqT/wkT/wvT contiguous -> fused [3072][1024]
  US* wkT = (US*)(ws + 26 * MB);
  US* wvT = (US*)(ws + 28 * MB);
  US* woT = (US*)(ws + 30 * MB);
  US* qh  = (US*)(ws + 32 * MB);  // [B,H,S,D] (pre-scaled by log2e)
  US* kh  = (US*)(ws + 40 * MB);  // [B,H,S,D]
  US* vt  = (US*)(ws + 48 * MB);  // [B,H,D,S]
  US* ao  = (US*)(ws + 56 * MB);  // [B*S, 1024]

  prep_kernel<<<7168, 256, 0, stream>>>(q, k, v, wq, wk, wv, wo,
                                        qb, kb, vb, wqT, wkT, wvT, woT);
  gemm_qkv_kernel<<<dim3(32, 24), 256, 0, stream>>>(qb, kb, vb, wqT,
                                                    bq, bk, bv, qh, kh, vt);
  attn_kernel<<<dim3(32, 24), 256, 0, stream>>>(qh, kh, vt, ao);
  gemm_out_kernel<<<dim3(32, 16), 256, 0, stream>>>(ao, woT, bo, out);
}

// Round 8
// 208.025 us; speedup vs baseline: 1.0041x; 1.0041x over previous
//
#include <hip/hip_runtime.h>
#include <stdint.h>

#define AS1q __attribute__((address_space(1)))
#define AS3q __attribute__((address_space(3)))

typedef unsigned short US;
typedef __bf16 bf16x8 __attribute__((ext_vector_type(8)));
typedef float f32x4 __attribute__((ext_vector_type(4)));
typedef float f32x16 __attribute__((ext_vector_type(16)));
typedef float f32x2 __attribute__((ext_vector_type(2)));
typedef __bf16 bf16x2 __attribute__((ext_vector_type(2)));

#define LOG2E 1.44269504088896340736f

__device__ __forceinline__ US f2bf(float f) {
  union { float f; uint32_t u; } c; c.f = f;
  uint32_t u = c.u;
  return (US)((u + 0x7fffu + ((u >> 16) & 1u)) >> 16);
}

__device__ __forceinline__ bf16x8 asb(uint4 u) {
  union { uint4 u; bf16x8 b; } c; c.u = u; return c.b;
}

__device__ __forceinline__ uint32_t pk2(float a, float b) {
  f32x2 fv; fv[0] = a; fv[1] = b;
  bf16x2 bb = __builtin_convertvector(fv, bf16x2);
  union { bf16x2 b; uint32_t u; } c; c.b = bb; return c.u;
}

__device__ __forceinline__ void gload16(const void* g, void* l) {
  __builtin_amdgcn_global_load_lds((AS1q void*)(void*)g, (AS3q void*)l, 16, 0, 0);
}

// ------------- prep: fused q/k/v fp32->bf16 + 4 weight transposes -------------
__global__ void prep_kernel(const float* __restrict__ q, const float* __restrict__ k,
                            const float* __restrict__ v,
                            const float* __restrict__ w0, const float* __restrict__ w1,
                            const float* __restrict__ w2, const float* __restrict__ w3,
                            US* __restrict__ qb, US* __restrict__ kb, US* __restrict__ vb,
                            US* __restrict__ t0, US* __restrict__ t1,
                            US* __restrict__ t2, US* __restrict__ t3) {
  __shared__ US T[64 * 68];
  const int bx = blockIdx.x;
  const int t = threadIdx.x;
  if (bx < 6144) {
    const int ten = bx >> 11, chunk = bx & 2047;
    const float* s; US* d;
    if (ten == 0)      { s = q; d = qb; }
    else if (ten == 1) { s = k; d = kb; }
    else               { s = v; d = vb; }
    int i = (chunk * 256 + t) * 8;
    float4 f0 = *(const float4*)&s[i];
    float4 f1 = *(const float4*)&s[i + 4];
    ushort4 u0, u1;
    u0.x = f2bf(f0.x); u0.y = f2bf(f0.y); u0.z = f2bf(f0.z); u0.w = f2bf(f0.w);
    u1.x = f2bf(f1.x); u1.y = f2bf(f1.y); u1.z = f2bf(f1.z); u1.w = f2bf(f1.w);
    *(ushort4*)&d[i] = u0;
    *(ushort4*)&d[i + 4] = u1;
    return;
  }
  const int idx = bx - 6144;
  const int wsel = idx >> 8, rem = idx & 255;
  const int n0 = (rem & 15) * 64, k0 = (rem >> 4) * 64;
  const float* W; US* Wt;
  if (wsel == 0)      { W = w0; Wt = t0; }
  else if (wsel == 1) { W = w1; Wt = t1; }
  else if (wsel == 2) { W = w2; Wt = t2; }
  else                { W = w3; Wt = t3; }
#pragma unroll
  for (int it = 0; it < 4; ++it) {
    int p = t + it * 256;
    int row = p >> 4, c4 = (p & 15) * 4;
    float4 f = *(const float4*)&W[(k0 + row) * 1024 + n0 + c4];
    ushort4 u;
    u.x = f2bf(f.x); u.y = f2bf(f.y); u.z = f2bf(f.z); u.w = f2bf(f.w);
    *(ushort4*)&T[row * 68 + c4] = u;
  }
  __syncthreads();
#pragma unroll
  for (int it = 0; it < 4; ++it) {
    int p = t + it * 256;
    int rn = p >> 4, ck = (p & 15) * 4;
    ushort4 o;
    o.x = T[(ck + 0) * 68 + rn];
    o.y = T[(ck + 1) * 68 + rn];
    o.z = T[(ck + 2) * 68 + rn];
    o.w = T[(ck + 3) * 68 + rn];
    *(ushort4*)&Wt[(n0 + rn) * 1024 + k0 + ck] = o;
  }
}

// ------------- GEMM core: 128x128 tile, BK=32, m97-style global_load_lds -------------
template <bool SWAP>
__device__ __forceinline__ void gemm_core(const US* A, const US* Wt,
                                          int m0, int n0, US* As, US* Bs,
                                          f32x4 acc[4][4]) {
  const int tid = threadIdx.x;
  const int wave = tid >> 6, lane = tid & 63;
  const int quad = lane >> 4, l16 = lane & 15;
  const int wm = wave >> 1, wn = wave & 1;
#pragma unroll
  for (int i = 0; i < 4; ++i)
#pragma unroll
    for (int j = 0; j < 4; ++j) acc[i][j] = (f32x4)0.0f;
  const int p = wave * 64 + lane;
  const int arow0 = p >> 2, koff = (p & 3) * 8;
  for (int k0 = 0; k0 < 1024; k0 += 32) {
    gload16(A + (m0 + arow0) * 1024 + k0 + koff, As + wave * 512);
    gload16(A + (m0 + arow0 + 64) * 1024 + k0 + koff, As + 2048 + wave * 512);
    gload16(Wt + (n0 + arow0) * 1024 + k0 + koff, Bs + wave * 512);
    gload16(Wt + (n0 + arow0 + 64) * 1024 + k0 + koff, Bs + 2048 + wave * 512);
    __syncthreads();
    uint4 af[4], bf_[4];
#pragma unroll
    for (int mt = 0; mt < 4; ++mt)
      af[mt] = *(const uint4*)&As[(wm * 64 + mt * 16 + l16) * 32 + quad * 8];
#pragma unroll
    for (int nt = 0; nt < 4; ++nt)
      bf_[nt] = *(const uint4*)&Bs[(wn * 64 + nt * 16 + l16) * 32 + quad * 8];
#pragma unroll
    for (int i = 0; i < 4; ++i)
#pragma unroll
      for (int j = 0; j < 4; ++j) {
        if (SWAP)
          acc[i][j] = __builtin_amdgcn_mfma_f32_16x16x32_bf16(asb(bf_[i]), asb(af[j]),
                                                              acc[i][j], 0, 0, 0);
        else
          acc[i][j] = __builtin_amdgcn_mfma_f32_16x16x32_bf16(asb(af[i]), asb(bf_[j]),
                                                              acc[i][j], 0, 0, 0);
      }
    __syncthreads();
  }
}

// Fused QKV projection (N=3072). Q is scaled by log2(e) so attn can use raw exp2.
__global__ __launch_bounds__(256, 4) void gemm_qkv_kernel(
    const US* __restrict__ qb, const US* __restrict__ kb, const US* __restrict__ vb,
    const US* __restrict__ wfT,
    const float* __restrict__ bq, const float* __restrict__ bk, const float* __restrict__ bv,
    US* __restrict__ qh, US* __restrict__ kh, US* __restrict__ vt) {
  __shared__ __align__(16) US As[4096], Bs[4096];
  const int m0 = blockIdx.x * 128, n0 = blockIdx.y * 128;
  const int which = n0 >> 10;
  const int nl0 = n0 & 1023;
  const US* A = (which == 0) ? qb : (which == 1) ? kb : vb;
  const float* bias = (which == 0) ? bq : (which == 1) ? bk : bv;
  const int tid = threadIdx.x, wave = tid >> 6, lane = tid & 63;
  const int quad = lane >> 4, l16 = lane & 15;
  const int wm = wave >> 1, wn = wave & 1;
  f32x4 acc[4][4];
  if (which == 2) {
    gemm_core<true>(A, wfT, m0, n0, As, Bs, acc);
#pragma unroll
    for (int nt = 0; nt < 4; ++nt) {
      int dg = nl0 + wn * 64 + nt * 16 + quad * 4;
#pragma unroll
      for (int r = 0; r < 4; ++r) {
        int d = dg + r;
        float bval = bias[d];
        int hh = d >> 6, dd = d & 63;
#pragma unroll
        for (int mt = 0; mt < 4; ++mt) {
          int sg = m0 + wm * 64 + mt * 16;
          int bb = sg >> 11, ss = sg & 2047;
          vt[(((size_t)bb * 16 + hh) * 64 + dd) * 2048 + ss + l16] =
              f2bf(acc[nt][mt][r] + bval);
        }
      }
    }
  } else {
    gemm_core<false>(A, wfT, m0, n0, As, Bs, acc);
    US* O = (which == 0) ? qh : kh;
    const float scale = (which == 0) ? LOG2E : 1.0f;
#pragma unroll
    for (int nt = 0; nt < 4; ++nt) {
      int nl = nl0 + wn * 64 + nt * 16 + l16;
      float bval = bias[nl];
      int hh = nl >> 6, d = nl & 63;
#pragma unroll
      for (int mt = 0; mt < 4; ++mt) {
#pragma unroll
        for (int r = 0; r < 4; ++r) {
          int m = m0 + wm * 64 + mt * 16 + quad * 4 + r;
          int bb = m >> 11, s = m & 2047;
          O[((bb * 16 + hh) * 2048 + s) * 64 + d] = f2bf((acc[mt][nt][r] + bval) * scale);
        }
      }
    }
  }
}

// Output projection: ao bf16 [4096][1024] @ woT + bo -> fp32 out
__global__ __launch_bounds__(256, 4) void gemm_out_kernel(
    const US* __restrict__ ao, const US* __restrict__ woT,
    const float* __restrict__ bo, float* __restrict__ out) {
  __shared__ __align__(16) US As[4096], Bs[2048];
  const int m0 = blockIdx.x * 128, n0 = blockIdx.y * 64;
  const int tid = threadIdx.x;
  const int wave = tid >> 6, lane = tid & 63;
  const int quad = lane >> 4, l16 = lane & 15;
  f32x4 acc[2][4];
#pragma unroll
  for (int i = 0; i < 2; ++i)
#pragma unroll
    for (int j = 0; j < 4; ++j) acc[i][j] = (f32x4)0.0f;
  const int arow0 = tid >> 2, koff = (tid & 3) * 8;
  for (int k0 = 0; k0 < 1024; k0 += 32) {
    gload16(ao + (m0 + arow0) * 1024 + k0 + koff, As + wave * 512);
    gload16(ao + (m0 + arow0 + 64) * 1024 + k0 + koff, As + 2048 + wave * 512);
    gload16(woT + (n0 + arow0) * 1024 + k0 + koff, Bs + wave * 512);
    __syncthreads();
    uint4 af[2], bf_[4];
#pragma unroll
    for (int mt = 0; mt < 2; ++mt)
      af[mt] = *(const uint4*)&As[(wave * 32 + mt * 16 + l16) * 32 + quad * 8];
#pragma unroll
    for (int nt = 0; nt < 4; ++nt)
      bf_[nt] = *(const uint4*)&Bs[(nt * 16 + l16) * 32 + quad * 8];
#pragma unroll
    for (int mt = 0; mt < 2; ++mt)
#pragma unroll
      for (int nt = 0; nt < 4; ++nt)
        acc[mt][nt] = __builtin_amdgcn_mfma_f32_16x16x32_bf16(asb(af[mt]), asb(bf_[nt]),
                                                              acc[mt][nt], 0, 0, 0);
    __syncthreads();
  }
#pragma unroll
  for (int nt = 0; nt < 4; ++nt) {
    int n = n0 + nt * 16 + l16;
    float bval = bo[n];
#pragma unroll
    for (int mt = 0; mt < 2; ++mt) {
#pragma unroll
      for (int r = 0; r < 4; ++r) {
        int m = m0 + wave * 32 + mt * 16 + quad * 4 + r;
        out[m * 1024 + n] = acc[mt][nt][r] + bval;
      }
    }
  }
}

// ------------- causal attention: 256 thr, S^T/O^T form, 128 keys/iter ----------------
// qh (pre-scaled by log2e)/kh: [bh][s][64]; vt: [bh][64][s]; aout: [b*s][1024] bf16
// Block (bh, j): q-tiles {31-j, j} -> every block does exactly 17 pair-iterations.
// waves: w_m in {0,1} = 32-q strip; w_k in {0,1} = 64-key half of the 128-key step.
// S^T = K·Q^T (C: col=q, row=key); P^T fed to O^T = V^T·P^T via in-register
// half-wave exchange (no LDS P round-trip). 32x32x16 layouts per m74/m101.
__global__ __launch_bounds__(256, 2) void attn_kernel(
    const US* __restrict__ qh, const US* __restrict__ kh,
    const US* __restrict__ vt, US* __restrict__ aout) {
  // arena: Ks dbuf [2][128*64] (32 KB) | Vs dbuf [2][64*128] (32 KB) | Qs (8 KB)
  // epilogue overlays Oex[2][64][68] f32 + lEx[2][64] onto the dead K/V region.
  __shared__ __align__(16) char arena[73728];
  US* KsA = (US*)arena;
  US* VsA = (US*)(arena + 32768);
  US* Qs  = (US*)(arena + 65536);
  float* Oex = (float*)arena;                  // [2][64][68]
  float* lEx = (float*)(arena + 34816);        // [2][64]

  const int tid = threadIdx.x;
  const int wave = tid >> 6, lane = tid & 63;
  const int l31 = lane & 31, lh = lane >> 5;
  const int w_m = wave & 1, w_k = wave >> 1;
  const int bh = blockIdx.x;
  const int b = bh >> 4, h = bh & 15;
  const int jg = blockIdx.y;

  const US* gkb = kh + (size_t)bh * 2048 * 64;
  const US* gvb = vt + (size_t)bh * 64 * 2048;

  for (int ei = 0; ei < 2; ++ei) {
    const int qt = ei ? jg : (31 - jg);
    const int q0 = qt * 64;
    const int nit = (qt >> 1) + 1;   // 128-key pair iterations
    __syncthreads();  // previous tile's epilogue reads / buffer reuse
    {
      const US* gq = qh + ((size_t)bh * 2048 + q0) * 64;
#pragma unroll
      for (int ro = 0; ro < 2; ++ro) {
        int p = tid + ro * 256;
        int row = p >> 3, c = (p & 7) ^ (row & 7);
        gload16(gq + row * 64 + c * 8, Qs + ro * 2048 + wave * 512);
      }
#pragma unroll
      for (int ro = 0; ro < 4; ++ro) {
        int p = tid + ro * 256;
        int row = p >> 3, c = (p & 7) ^ (row & 7);
        gload16(gkb + row * 64 + c * 8, KsA + ro * 2048 + wave * 512);
      }
#pragma unroll
      for (int ro = 0; ro < 4; ++ro) {
        int p = tid + ro * 256;
        int row = p >> 4, c = (p & 15) ^ (row & 15);
        gload16(gvb + row * 2048 + c * 8, VsA + ro * 2048 + wave * 512);
      }
    }
    __syncthreads();

    // hoist Q B-fragments: B[k=d][n=q], q = q0 + 32*w_m + l31
    const int qrow = w_m * 32 + l31;
    uint4 bq[4];
#pragma unroll
    for (int s = 0; s < 4; ++s)
      bq[s] = *(const uint4*)&Qs[qrow * 64 + (((2 * s + lh) ^ (qrow & 7)) * 8)];
    const int q_g = q0 + qrow;

    float l_lane = 0.0f;
    f32x16 Oa0 = (f32x16)0.0f, Oa1 = (f32x16)0.0f;

    for (int it = 0; it < nit; ++it) {
      const int cb = it & 1;
      const int kb = it * 128;
      if (it) __syncthreads();
      if (it + 1 < nit) {
        const US* gk = gkb + (kb + 128) * 64;
        const US* gv = gvb + (kb + 128);
        US* kd = KsA + (cb ^ 1) * 8192;
        US* vd = VsA + (cb ^ 1) * 8192;
#pragma unroll
        for (int ro = 0; ro < 4; ++ro) {
          int p = tid + ro * 256;
          int row = p >> 3, c = (p & 7) ^ (row & 7);
          gload16(gk + row * 64 + c * 8, kd + ro * 2048 + wave * 512);
        }
#pragma unroll
        for (int ro = 0; ro < 4; ++ro) {
          int p = tid + ro * 256;
          int row = p >> 4, c = (p & 15) ^ (row & 15);
          gload16(gv + row * 2048 + c * 8, vd + ro * 2048 + wave * 512);
        }
      }
      const US* Kc = KsA + cb * 8192;
      const US* Vc = VsA + cb * 8192;

      // S^T = K·Q^T : two 32-key tiles per wave (64 keys)
      f32x16 sa0 = (f32x16)0.0f, sa1 = (f32x16)0.0f;
#pragma unroll
      for (int s = 0; s < 4; ++s) {
        int kr0 = w_k * 64 + l31;
        uint4 ka0 = *(const uint4*)&Kc[kr0 * 64 + (((2 * s + lh) ^ (kr0 & 7)) * 8)];
        sa0 = __builtin_amdgcn_mfma_f32_32x32x16_bf16(asb(ka0), asb(bq[s]), sa0, 0, 0, 0);
      }
#pragma unroll
      for (int s = 0; s < 4; ++s) {
        int kr1 = w_k * 64 + 32 + l31;
        uint4 ka1 = *(const uint4*)&Kc[kr1 * 64 + (((2 * s + lh) ^ (kr1 & 7)) * 8)];
        sa1 = __builtin_amdgcn_mfma_f32_32x32x16_bf16(asb(ka1), asb(bq[s]), sa1, 0, 0, 0);
      }

      // exp2 + causal zeroing (diagonal only on last iteration)
      const bool diag = (it == nit - 1);
      float e[2][16];
#pragma unroll
      for (int ta = 0; ta < 2; ++ta) {
        const int kbase = kb + w_k * 64 + ta * 32 + 4 * lh;
#pragma unroll
        for (int r = 0; r < 16; ++r) {
          float sv = ta ? sa1[r] : sa0[r];
          float ev = __builtin_amdgcn_exp2f(sv);
          if (diag) {
            int key_g = kbase + (r & 3) + 8 * (r >> 2);
            if (key_g > q_g) ev = 0.0f;
          }
          e[ta][r] = ev;
          l_lane += ev;
        }
      }

      // P^T B-frags via half-wave exchange, then O^T += V^T · P^T
#pragma unroll
      for (int ta = 0; ta < 2; ++ta) {
#pragma unroll
        for (int s2 = 0; s2 < 2; ++s2) {
          uint32_t PA0 = pk2(e[ta][8 * s2 + 0], e[ta][8 * s2 + 1]);
          uint32_t PA1 = pk2(e[ta][8 * s2 + 2], e[ta][8 * s2 + 3]);
          uint32_t PB0 = pk2(e[ta][8 * s2 + 4], e[ta][8 * s2 + 5]);
          uint32_t PB1 = pk2(e[ta][8 * s2 + 6], e[ta][8 * s2 + 7]);
          uint32_t XA0 = (uint32_t)__shfl_xor((int)PA0, 32, 64);
          uint32_t XA1 = (uint32_t)__shfl_xor((int)PA1, 32, 64);
          uint32_t XB0 = (uint32_t)__shfl_xor((int)PB0, 32, 64);
          uint32_t XB1 = (uint32_t)__shfl_xor((int)PB1, 32, 64);
          uint4 bp;
          bp.x = lh ? XB0 : PA0;
          bp.y = lh ? XB1 : PA1;
          bp.z = lh ? PB0 : XA0;
          bp.w = lh ? PB1 : XA1;
          const int c_log = w_k * 8 + ta * 4 + s2 * 2 + lh;
          int vr0 = l31;
          uint4 va0 = *(const uint4*)&Vc[vr0 * 128 + ((c_log ^ (vr0 & 15)) * 8)];
          Oa0 = __builtin_amdgcn_mfma_f32_32x32x16_bf16(asb(va0), asb(bp), Oa0, 0, 0, 0);
          int vr1 = 32 + l31;
          uint4 va1 = *(const uint4*)&Vc[vr1 * 128 + ((c_log ^ (vr1 & 15)) * 8)];
          Oa1 = __builtin_amdgcn_mfma_f32_32x32x16_bf16(asb(va1), asb(bp), Oa1, 0, 0, 0);
        }
      }
    }

    // l: combine lane halves (each half saw 16 of every 32 keys)
    float l_q = l_lane + __shfl_xor(l_lane, 32, 64);

    __syncthreads();  // K/V buffers dead; overlay epilogue exchange
    {
      float* myO = Oex + w_k * (64 * 68);
      int q_idx = w_m * 32 + l31;
#pragma unroll
      for (int r = 0; r < 16; ++r) {
        int dr = 4 * lh + (r & 3) + 8 * (r >> 2);
        myO[q_idx * 68 + dr] = Oa0[r];
        myO[q_idx * 68 + 32 + dr] = Oa1[r];
      }
      if (lh == 0) lEx[w_k * 64 + q_idx] = l_q;
    }
    __syncthreads();
    {
      int q_idx = tid >> 2;
      int dseg = (tid & 3) * 16;
      float inv = 1.0f / (lEx[q_idx] + lEx[64 + q_idx]);
      union { US s[16]; uint4 v[2]; } ob;
#pragma unroll
      for (int t2 = 0; t2 < 16; ++t2) {
        float o = Oex[q_idx * 68 + dseg + t2] + Oex[64 * 68 + q_idx * 68 + dseg + t2];
        ob.s[t2] = f2bf(o * inv);
      }
      US* dst = aout + ((size_t)b * 2048 + q0 + q_idx) * 1024 + h * 64 + dseg;
      *(uint4*)dst = ob.v[0];
      *(uint4*)(dst + 8) = ob.v[1];
    }
  }
}

extern "C" void kernel_launch(void* const* d_in, const int* in_sizes, int n_in,
                              void* d_out, int out_size, void* d_ws, size_t ws_size,
                              hipStream_t stream) {
  const float* q  = (const float*)d_in[0];
  const float* k  = (const float*)d_in[1];
  const float* v  = (const float*)d_in[2];
  const float* wq = (const float*)d_in[3];
  const float* bq = (const float*)d_in[4];
  const float* wk = (const float*)d_in[5];
  const float* bk = (const float*)d_in[6];
  const float* wv = (const float*)d_in[7];
  const float* bv = (const float*)d_in[8];
  const float* wo = (const float*)d_in[9];
  const float* bo = (const float*)d_in[10];
  float* out = (float*)d_out;

  char* ws = (char*)d_ws;
  const size_t MB = 1024 * 1024;
  US* qb  = (US*)(ws + 0 * MB);
  US* kb  = (US*)(ws + 8 * MB);
  US* vb  = (US*)(ws + 16 * MB);
  US* wqT = (US*)(ws + 24 * MB);  // wqT/wkT/wvT contiguous -> fused [3072][1024]
  US* wkT = (US*)(ws + 26 * MB);
  US* wvT = (US*)(ws + 28 * MB);
  US* woT = (US*)(ws + 30 * MB);
  US* qh  = (US*)(ws + 32 * MB);  // [B,H,S,D] (pre-scaled by log2e)
  US* kh  = (US*)(ws + 40 * MB);  // [B,H,S,D]
  US* vt  = (US*)(ws + 48 * MB);  // [B,H,D,S]
  US* ao  = (US*)(ws + 56 * MB);  // [B*S, 1024]

  prep_kernel<<<7168, 256, 0, stream>>>(q, k, v, wq, wk, wv, wo,
                                        qb, kb, vb, wqT, wkT, wvT, woT);
  gemm_qkv_kernel<<<dim3(32, 24), 256, 0, stream>>>(qb, kb, vb, wqT,
                                                    bq, bk, bv, qh, kh, vt);
  attn_kernel<<<dim3(32, 16), 256, 0, stream>>>(qh, kh, vt, ao);
  gemm_out_kernel<<<dim3(32, 16), 256, 0, stream>>>(ao, woT, bo, out);
}